// Round 2
// baseline (3472.013 us; speedup 1.0000x reference)
//
#include <hip/hip_runtime.h>
#include <hip/hip_bf16.h>

// ---------------- constants (problem: B=8,S=8192 -> N=65536, D=512, E=209) ----
#define DK 512        // feature dim
#define TM 32         // tokens per block (main kernel)
#define KC 32         // K chunk
#define EPAD 224      // padded expert count (>= E)
#define XS 36         // x row stride in LDS (floats), padded
#define WSTR 36       // w row stride in LDS (floats), padded
#define LP 225        // logits row stride in LDS

// ---------------------------------------------------------------- init -------
extern "C" __global__ void moe_init(float* hist, float* probsum, int* cnt) {
    int t = threadIdx.x;
    if (t < EPAD) { hist[t] = 0.f; probsum[t] = 0.f; }
    if (t == 0) *cnt = 0;
}

// ---------------------------------------------------------------- main -------
// 256 threads: thread t -> tx = t&31 (expert dim, 7 experts each: e = tx*7+j),
//                          ty = t>>5 (token dim, 4 tokens each: r = ty*4+i)
extern "C" __global__ void moe_main(const float* __restrict__ x,
                                    const float* __restrict__ w,
                                    float* __restrict__ out,
                                    float* __restrict__ hist,
                                    float* __restrict__ probsum_g,
                                    int* __restrict__ flag_cnt,
                                    int* __restrict__ flag_list,
                                    int flag_cap, int N, int E)
{
    __shared__ float smem[TM * XS + EPAD * WSTR];   // 9216 floats = 36.9 KB
    float* xs = smem;                 // [TM][XS]
    float* wl = smem + TM * XS;       // [EPAD][WSTR]

    const int t  = threadIdx.x;
    const int tx = t & 31;
    const int ty = t >> 5;
    const int tok0 = blockIdx.x * TM;

    float acc[4][7];
    #pragma unroll
    for (int i = 0; i < 4; ++i)
        #pragma unroll
        for (int j = 0; j < 7; ++j) acc[i][j] = 0.f;

    for (int k0 = 0; k0 < DK; k0 += KC) {
        __syncthreads();   // previous chunk's reads done before overwrite
        // ---- stage x chunk (32 tokens x 32 k) : one float4 per thread,
        //      and emit the f32 x_flat copy on the way through.
        {
            int r = t >> 3, k4 = t & 7;
            size_t goff = (size_t)(tok0 + r) * DK + k0 + k4 * 4;
            float4 v = *reinterpret_cast<const float4*>(x + goff);
            *reinterpret_cast<float4*>(&xs[r * XS + k4 * 4]) = v;
            *reinterpret_cast<float4*>(out + goff) = v;
        }
        // ---- stage w chunk (224 experts x 32 k) : 7 float4 per thread
        #pragma unroll
        for (int i = 0; i < 7; ++i) {
            int idx4 = t + 256 * i;
            int e = idx4 >> 3, k4 = idx4 & 7;
            float4 v = make_float4(0.f, 0.f, 0.f, 0.f);
            if (e < E) v = *reinterpret_cast<const float4*>(w + (size_t)e * DK + k0 + k4 * 4);
            *reinterpret_cast<float4*>(&wl[e * WSTR + k4 * 4]) = v;
        }
        __syncthreads();
        // ---- FMA inner loop
        #pragma unroll
        for (int k4 = 0; k4 < 8; ++k4) {
            float4 xa[4], wb[7];
            #pragma unroll
            for (int i = 0; i < 4; ++i)
                xa[i] = *reinterpret_cast<const float4*>(&xs[(ty * 4 + i) * XS + k4 * 4]);
            #pragma unroll
            for (int j = 0; j < 7; ++j)
                wb[j] = *reinterpret_cast<const float4*>(&wl[(tx * 7 + j) * WSTR + k4 * 4]);
            #pragma unroll
            for (int i = 0; i < 4; ++i)
                #pragma unroll
                for (int j = 0; j < 7; ++j)
                    acc[i][j] += xa[i].x * wb[j].x + xa[i].y * wb[j].y
                               + xa[i].z * wb[j].z + xa[i].w * wb[j].w;
        }
    }
    __syncthreads();

    // -------- phase 2: softmax / argmax / reductions (reuse LDS) ------------
    float* logits = smem;                 // [TM][LP]
    float* tok_m  = smem + TM * LP;       // [TM]
    float* tok_s  = tok_m + TM;           // [TM]
    float* ps_l   = tok_s + TM;           // [EPAD]

    #pragma unroll
    for (int i = 0; i < 4; ++i)
        #pragma unroll
        for (int j = 0; j < 7; ++j)
            logits[(ty * 4 + i) * LP + tx * 7 + j] = acc[i][j];
    if (t < EPAD) ps_l[t] = 0.f;
    __syncthreads();

    // per-token reduce: 8 threads per token (lanes stay inside one wave)
    {
        int r = t >> 3, sub = t & 7;
        float m1 = -1e30f, m2 = -1e30f;
        int i1 = 0x7fffffff;
        for (int e = sub; e < E; e += 8) {
            float v = logits[r * LP + e];
            if (v > m1) { m2 = m1; m1 = v; i1 = e; }
            else if (v > m2) { m2 = v; }
        }
        #pragma unroll
        for (int mask = 1; mask < 8; mask <<= 1) {
            float om1 = __shfl_xor(m1, mask);
            float om2 = __shfl_xor(m2, mask);
            int   oi1 = __shfl_xor(i1, mask);
            if (om1 > m1 || (om1 == m1 && oi1 < i1)) {
                m2 = fmaxf(m1, om2);
                m1 = om1; i1 = oi1;
            } else {
                m2 = fmaxf(m2, om1);
            }
        }
        float s = 0.f;
        for (int e = sub; e < E; e += 8) s += __expf(logits[r * LP + e] - m1);
        #pragma unroll
        for (int mask = 1; mask < 8; mask <<= 1) s += __shfl_xor(s, mask);

        if (sub == 0) {
            tok_m[r] = m1; tok_s[r] = s;
            int tok = tok0 + r;
            out[(size_t)N * DK + tok]     = 1.0f / s;       // gate_scores = max prob
            out[(size_t)N * DK + N + tok] = (float)i1;      // expert index
            atomicAdd(&hist[i1], 1.0f);
            if (m1 - m2 < 2e-4f) {                          // ambiguous argmax
                int pos = atomicAdd(flag_cnt, 1);
                if (pos < flag_cap) flag_list[pos] = tok;
            }
        }
    }
    __syncthreads();

    // per-expert prob partial sums
    #pragma unroll
    for (int i = 0; i < 4; ++i) {
        float m = tok_m[ty * 4 + i];
        float sinv = 1.0f / tok_s[ty * 4 + i];
        #pragma unroll
        for (int j = 0; j < 7; ++j) {
            int e = tx * 7 + j;
            if (e < E) atomicAdd(&ps_l[e], __expf(acc[i][j] - m) * sinv);
        }
    }
    __syncthreads();
    if (t < E) atomicAdd(&probsum_g[t], ps_l[t]);
}

// ------------------------------------------------------------- refine --------
// For tokens whose f32 top-2 gap < tau: recompute all E dots in f64 (exact for
// f32 products), fix expert index + histogram if the argmax differs.
extern "C" __global__ void moe_refine(const float* __restrict__ x,
                                      const float* __restrict__ w,
                                      float* __restrict__ hist,
                                      const int* __restrict__ flag_cnt,
                                      const int* __restrict__ flag_list,
                                      int flag_cap,
                                      float* __restrict__ out,
                                      int N, int E)
{
    __shared__ float  xsh[DK];
    __shared__ double rv[256];
    __shared__ int    ri[256];
    int nf = *flag_cnt; if (nf > flag_cap) nf = flag_cap;
    const int tid = threadIdx.x;

    for (int li = blockIdx.x; li < nf; li += gridDim.x) {
        int tok = flag_list[li];
        for (int k = tid; k < DK; k += 256) xsh[k] = x[(size_t)tok * DK + k];
        __syncthreads();
        double a = -1e300;
        if (tid < E) {
            a = 0.0;
            const float* wr = w + (size_t)tid * DK;
            for (int k = 0; k < DK; ++k) a += (double)xsh[k] * (double)wr[k];
        }
        rv[tid] = a; ri[tid] = tid;
        __syncthreads();
        for (int s = 128; s > 0; s >>= 1) {
            if (tid < s) {
                double vb = rv[tid + s]; int ib = ri[tid + s];
                double va = rv[tid];     int ia = ri[tid];
                if (vb > va || (vb == va && ib < ia)) { rv[tid] = vb; ri[tid] = ib; }
            }
            __syncthreads();
        }
        if (tid == 0) {
            int newi = ri[0];
            int oldi = (int)out[(size_t)N * DK + N + tok];
            if (newi != oldi) {
                atomicAdd(&hist[oldi], -1.0f);
                atomicAdd(&hist[newi],  1.0f);
                out[(size_t)N * DK + N + tok] = (float)newi;
            }
        }
        __syncthreads();
    }
}

// ------------------------------------------------------------ finalize -------
extern "C" __global__ void moe_final(const float* __restrict__ hist,
                                     const float* __restrict__ probsum,
                                     const float* __restrict__ ec_in,
                                     const float* __restrict__ gps_in,
                                     float* __restrict__ out,
                                     int N, int E)
{
    __shared__ double red[256];
    int t = threadIdx.x;
    double p = 0.0;
    if (t < E) p = (double)hist[t] * (double)probsum[t];
    red[t] = p;
    __syncthreads();
    for (int s = 128; s > 0; s >>= 1) {
        if (t < s) red[t] += red[t + s];
        __syncthreads();
    }
    size_t base = (size_t)N * DK + 2 * (size_t)N;
    if (t == 0) {
        double loss = (double)E * red[0] / ((double)N * (double)N);
        out[base] = (float)loss;
    }
    if (t < E) {
        out[base + 1 + t]     = 0.9f * ec_in[t]  + 0.1f * hist[t];
        out[base + 1 + E + t] = 0.9f * gps_in[t] + 0.1f * probsum[t];
    }
}

// ------------------------------------------------------------- launch --------
extern "C" void kernel_launch(void* const* d_in, const int* in_sizes, int n_in,
                              void* d_out, int out_size, void* d_ws, size_t ws_size,
                              hipStream_t stream)
{
    const float* x   = (const float*)d_in[0];
    const float* w   = (const float*)d_in[1];
    const float* ec  = (const float*)d_in[2];
    const float* gps = (const float*)d_in[3];
    float* out = (float*)d_out;

    int E = in_sizes[2];              // 209
    int N = in_sizes[0] / DK;         // 65536

    float* hist    = (float*)d_ws;
    float* probsum = hist + EPAD;
    int*   cnt     = (int*)(probsum + EPAD);
    int*   list    = cnt + 1;
    long long cap_ll = ((long long)ws_size - 4LL * (EPAD + EPAD + 1)) / 4;
    int cap = cap_ll < 0 ? 0 : (cap_ll > 65536 ? 65536 : (int)cap_ll);

    moe_init  <<<1,      256, 0, stream>>>(hist, probsum, cnt);
    moe_main  <<<N / TM, 256, 0, stream>>>(x, w, out, hist, probsum, cnt, list, cap, N, E);
    moe_refine<<<256,    256, 0, stream>>>(x, w, hist, cnt, list, cap, out, N, E);
    moe_final <<<1,      256, 0, stream>>>(hist, probsum, ec, gps, out, N, E);
}

// Round 3
// 921.605 us; speedup vs baseline: 3.7674x; 3.7674x over previous
//
#include <hip/hip_runtime.h>
#include <hip/hip_bf16.h>

// ---------------- constants (problem: B=8,S=8192 -> N=65536, D=512, E=209) ----
#define DK 512        // feature dim
#define TM 32         // tokens per block (main kernel)
#define KC 32         // K chunk
#define EPAD 224      // padded expert count (>= E)
#define XS 36         // x row stride in LDS (floats), padded
#define WSTR 36       // w row stride in LDS (floats), padded
#define LP 225        // logits row stride in LDS

// ---------------------------------------------------------------- init -------
extern "C" __global__ void moe_init(float* hist, float* probsum, int* cnt) {
    int t = threadIdx.x;
    if (t < EPAD) { hist[t] = 0.f; probsum[t] = 0.f; }
    if (t == 0) *cnt = 0;
}

// ---------------------------------------------------------------- main -------
// 256 threads: thread t -> tx = t&31 (expert dim, 7 experts each: e = tx*7+j),
//                          ty = t>>5 (token dim, 4 tokens each: r = ty*4+i)
// __launch_bounds__(256,2): block=256, >=2 waves/EU -> VGPR cap 256.
// Without this hipcc assumed 1024-thr blocks -> 64 VGPRs -> scratch spill
// (R2: 7.3 GB spill writes, VALUBusy 6%).
extern "C" __global__ void __launch_bounds__(256, 2)
moe_main(const float* __restrict__ x,
         const float* __restrict__ w,
         float* __restrict__ out,
         float* __restrict__ hist,
         float* __restrict__ probsum_g,
         int* __restrict__ flag_cnt,
         int* __restrict__ flag_list,
         int flag_cap, int N, int E)
{
    __shared__ float smem[TM * XS + EPAD * WSTR];   // 9216 floats = 36.9 KB
    float* xs = smem;                 // [TM][XS]
    float* wl = smem + TM * XS;       // [EPAD][WSTR]

    const int t  = threadIdx.x;
    const int tx = t & 31;
    const int ty = t >> 5;
    const int tok0 = blockIdx.x * TM;

    float acc[4][7];
    #pragma unroll
    for (int i = 0; i < 4; ++i)
        #pragma unroll
        for (int j = 0; j < 7; ++j) acc[i][j] = 0.f;

    for (int k0 = 0; k0 < DK; k0 += KC) {
        __syncthreads();   // previous chunk's reads done before overwrite
        // ---- stage x chunk (32 tokens x 32 k) : one float4 per thread,
        //      and emit the f32 x_flat copy on the way through.
        {
            int r = t >> 3, k4 = t & 7;
            size_t goff = (size_t)(tok0 + r) * DK + k0 + k4 * 4;
            float4 v = *reinterpret_cast<const float4*>(x + goff);
            *reinterpret_cast<float4*>(&xs[r * XS + k4 * 4]) = v;
            *reinterpret_cast<float4*>(out + goff) = v;
        }
        // ---- stage w chunk (224 experts x 32 k) : 7 float4 per thread
        #pragma unroll
        for (int i = 0; i < 7; ++i) {
            int idx4 = t + 256 * i;
            int e = idx4 >> 3, k4 = idx4 & 7;
            float4 v = make_float4(0.f, 0.f, 0.f, 0.f);
            if (e < E) v = *reinterpret_cast<const float4*>(w + (size_t)e * DK + k0 + k4 * 4);
            *reinterpret_cast<float4*>(&wl[e * WSTR + k4 * 4]) = v;
        }
        __syncthreads();
        // ---- FMA inner loop
        #pragma unroll
        for (int k4 = 0; k4 < 8; ++k4) {
            float4 xa[4], wb[7];
            #pragma unroll
            for (int i = 0; i < 4; ++i)
                xa[i] = *reinterpret_cast<const float4*>(&xs[(ty * 4 + i) * XS + k4 * 4]);
            #pragma unroll
            for (int j = 0; j < 7; ++j)
                wb[j] = *reinterpret_cast<const float4*>(&wl[(tx * 7 + j) * WSTR + k4 * 4]);
            #pragma unroll
            for (int i = 0; i < 4; ++i)
                #pragma unroll
                for (int j = 0; j < 7; ++j)
                    acc[i][j] += xa[i].x * wb[j].x + xa[i].y * wb[j].y
                               + xa[i].z * wb[j].z + xa[i].w * wb[j].w;
        }
    }
    __syncthreads();

    // -------- phase 2: softmax / argmax / reductions (reuse LDS) ------------
    float* logits = smem;                 // [TM][LP]
    float* tok_m  = smem + TM * LP;       // [TM]
    float* tok_s  = tok_m + TM;           // [TM]
    float* ps_l   = tok_s + TM;           // [EPAD]

    #pragma unroll
    for (int i = 0; i < 4; ++i)
        #pragma unroll
        for (int j = 0; j < 7; ++j)
            logits[(ty * 4 + i) * LP + tx * 7 + j] = acc[i][j];
    if (t < EPAD) ps_l[t] = 0.f;
    __syncthreads();

    // per-token reduce: 8 threads per token (lanes stay inside one wave)
    {
        int r = t >> 3, sub = t & 7;
        float m1 = -1e30f, m2 = -1e30f;
        int i1 = 0x7fffffff;
        for (int e = sub; e < E; e += 8) {
            float v = logits[r * LP + e];
            if (v > m1) { m2 = m1; m1 = v; i1 = e; }
            else if (v > m2) { m2 = v; }
        }
        #pragma unroll
        for (int mask = 1; mask < 8; mask <<= 1) {
            float om1 = __shfl_xor(m1, mask);
            float om2 = __shfl_xor(m2, mask);
            int   oi1 = __shfl_xor(i1, mask);
            if (om1 > m1 || (om1 == m1 && oi1 < i1)) {
                m2 = fmaxf(m1, om2);
                m1 = om1; i1 = oi1;
            } else {
                m2 = fmaxf(m2, om1);
            }
        }
        float s = 0.f;
        for (int e = sub; e < E; e += 8) s += __expf(logits[r * LP + e] - m1);
        #pragma unroll
        for (int mask = 1; mask < 8; mask <<= 1) s += __shfl_xor(s, mask);

        if (sub == 0) {
            tok_m[r] = m1; tok_s[r] = s;
            int tok = tok0 + r;
            out[(size_t)N * DK + tok]     = 1.0f / s;       // gate_scores = max prob
            out[(size_t)N * DK + N + tok] = (float)i1;      // expert index
            atomicAdd(&hist[i1], 1.0f);
            if (m1 - m2 < 2e-4f) {                          // ambiguous argmax
                int pos = atomicAdd(flag_cnt, 1);
                if (pos < flag_cap) flag_list[pos] = tok;
            }
        }
    }
    __syncthreads();

    // per-expert prob partial sums
    #pragma unroll
    for (int i = 0; i < 4; ++i) {
        float m = tok_m[ty * 4 + i];
        float sinv = 1.0f / tok_s[ty * 4 + i];
        #pragma unroll
        for (int j = 0; j < 7; ++j) {
            int e = tx * 7 + j;
            if (e < E) atomicAdd(&ps_l[e], __expf(acc[i][j] - m) * sinv);
        }
    }
    __syncthreads();
    if (t < E) atomicAdd(&probsum_g[t], ps_l[t]);
}

// ------------------------------------------------------------- refine --------
// For tokens whose f32 top-2 gap < tau: recompute all E dots in f64 (exact for
// f32 products), fix expert index + histogram if the argmax differs.
extern "C" __global__ void __launch_bounds__(256)
moe_refine(const float* __restrict__ x,
           const float* __restrict__ w,
           float* __restrict__ hist,
           const int* __restrict__ flag_cnt,
           const int* __restrict__ flag_list,
           int flag_cap,
           float* __restrict__ out,
           int N, int E)
{
    __shared__ float  xsh[DK];
    __shared__ double rv[256];
    __shared__ int    ri[256];
    int nf = *flag_cnt; if (nf > flag_cap) nf = flag_cap;
    const int tid = threadIdx.x;

    for (int li = blockIdx.x; li < nf; li += gridDim.x) {
        int tok = flag_list[li];
        for (int k = tid; k < DK; k += 256) xsh[k] = x[(size_t)tok * DK + k];
        __syncthreads();
        double a = -1e300;
        if (tid < E) {
            a = 0.0;
            const float* wr = w + (size_t)tid * DK;
            for (int k = 0; k < DK; ++k) a += (double)xsh[k] * (double)wr[k];
        }
        rv[tid] = a; ri[tid] = tid;
        __syncthreads();
        for (int s = 128; s > 0; s >>= 1) {
            if (tid < s) {
                double vb = rv[tid + s]; int ib = ri[tid + s];
                double va = rv[tid];     int ia = ri[tid];
                if (vb > va || (vb == va && ib < ia)) { rv[tid] = vb; ri[tid] = ib; }
            }
            __syncthreads();
        }
        if (tid == 0) {
            int newi = ri[0];
            int oldi = (int)out[(size_t)N * DK + N + tok];
            if (newi != oldi) {
                atomicAdd(&hist[oldi], -1.0f);
                atomicAdd(&hist[newi],  1.0f);
                out[(size_t)N * DK + N + tok] = (float)newi;
            }
        }
        __syncthreads();
    }
}

// ------------------------------------------------------------ finalize -------
extern "C" __global__ void __launch_bounds__(256)
moe_final(const float* __restrict__ hist,
          const float* __restrict__ probsum,
          const float* __restrict__ ec_in,
          const float* __restrict__ gps_in,
          float* __restrict__ out,
          int N, int E)
{
    __shared__ double red[256];
    int t = threadIdx.x;
    double p = 0.0;
    if (t < E) p = (double)hist[t] * (double)probsum[t];
    red[t] = p;
    __syncthreads();
    for (int s = 128; s > 0; s >>= 1) {
        if (t < s) red[t] += red[t + s];
        __syncthreads();
    }
    size_t base = (size_t)N * DK + 2 * (size_t)N;
    if (t == 0) {
        double loss = (double)E * red[0] / ((double)N * (double)N);
        out[base] = (float)loss;
    }
    if (t < E) {
        out[base + 1 + t]     = 0.9f * ec_in[t]  + 0.1f * hist[t];
        out[base + 1 + E + t] = 0.9f * gps_in[t] + 0.1f * probsum[t];
    }
}

// ------------------------------------------------------------- launch --------
extern "C" void kernel_launch(void* const* d_in, const int* in_sizes, int n_in,
                              void* d_out, int out_size, void* d_ws, size_t ws_size,
                              hipStream_t stream)
{
    const float* x   = (const float*)d_in[0];
    const float* w   = (const float*)d_in[1];
    const float* ec  = (const float*)d_in[2];
    const float* gps = (const float*)d_in[3];
    float* out = (float*)d_out;

    int E = in_sizes[2];              // 209
    int N = in_sizes[0] / DK;         // 65536

    float* hist    = (float*)d_ws;
    float* probsum = hist + EPAD;
    int*   cnt     = (int*)(probsum + EPAD);
    int*   list    = cnt + 1;
    long long cap_ll = ((long long)ws_size - 4LL * (EPAD + EPAD + 1)) / 4;
    int cap = cap_ll < 0 ? 0 : (cap_ll > 65536 ? 65536 : (int)cap_ll);

    moe_init  <<<1,      256, 0, stream>>>(hist, probsum, cnt);
    moe_main  <<<N / TM, 256, 0, stream>>>(x, w, out, hist, probsum, cnt, list, cap, N, E);
    moe_refine<<<256,    256, 0, stream>>>(x, w, hist, cnt, list, cap, out, N, E);
    moe_final <<<1,      256, 0, stream>>>(hist, probsum, ec, gps, out, N, E);
}

// Round 4
// 250.583 us; speedup vs baseline: 13.8558x; 3.6778x over previous
//
#include <hip/hip_runtime.h>

// ---------------- constants (B=8,S=8192 -> N=65536, D=512, E=209) ------------
#define DK 512         // feature dim
#define TMB 64         // tokens per block
#define KB 32          // K per chunk (= one MFMA K-step)
#define NCHUNK (DK / KB)
#define EPAD 224       // padded experts: 14 panels x 16
#define LP 225         // logits row stride (f32), phase 2

typedef __attribute__((ext_vector_type(8))) short bf16x8;   // 8 bf16 = 4 VGPR
typedef __attribute__((ext_vector_type(4))) float f32x4;

__device__ __forceinline__ unsigned short f2b(float f) {   // f32 -> bf16 RNE
    unsigned u = __float_as_uint(f);
    return (unsigned short)((u + 0x7fffu + ((u >> 16) & 1u)) >> 16);
}
__device__ __forceinline__ float b2f(unsigned short h) {
    return __uint_as_float((unsigned)h << 16);
}
// split one float4 into hi/lo bf16 quads
__device__ __forceinline__ void split4(float4 v, ushort4& h, ushort4& lo) {
    h.x = f2b(v.x); h.y = f2b(v.y); h.z = f2b(v.z); h.w = f2b(v.w);
    lo.x = f2b(v.x - b2f(h.x)); lo.y = f2b(v.y - b2f(h.y));
    lo.z = f2b(v.z - b2f(h.z)); lo.w = f2b(v.w - b2f(h.w));
}
// swizzled byte offset in a [rows][32 bf16 = 64B] tile (m214 XOR pattern)
__device__ __forceinline__ int swz(int row, int colbyte) {
    return (row * 64 + colbyte) ^ ((row & 7) << 4);
}

// ---------------------------------------------------------------- init -------
extern "C" __global__ void moe_init(float* hist, float* probsum, int* cnt) {
    int t = threadIdx.x;
    if (t < EPAD) { hist[t] = 0.f; probsum[t] = 0.f; }
    if (t == 0) *cnt = 0;
}

// ---------------------------------------------------------------- main -------
// 256 thr = 4 waves, wave grid 2x2: wm owns 32 tokens (2 m-tiles),
// wn owns 7 expert panels of 16. bf16-split GEMM: hh + hl + lh terms.
extern "C" __global__ void __launch_bounds__(256, 3)
moe_main(const float* __restrict__ x,
         const float* __restrict__ w,
         float* __restrict__ out,
         float* __restrict__ hist,
         float* __restrict__ probsum_g,
         int* __restrict__ flag_cnt,
         int* __restrict__ flag_list,
         int flag_cap, int N, int E)
{
    __shared__ float4 smem4[2304];            // 36864 B, GEMM tiles / logits
    char* lds = (char*)smem4;
    char* Ahi = lds;                          // 64 x 64B  = 4096
    char* Alo = lds + 4096;                   // 4096
    char* Bhi = lds + 8192;                   // 224 x 64B = 14336
    char* Blo = lds + 22528;                  // 14336
    __shared__ float ps_l[EPAD];
    __shared__ float tok_m[32], tok_s[32];

    const int t   = threadIdx.x;
    const int l   = t & 63;
    const int wid = t >> 6;
    const int wm  = wid >> 1;                 // M half
    const int wn  = wid & 1;                  // N half
    const int lrow = l & 15;
    const int coff = (l >> 4) * 16;           // byte col of this lane's frag
    const int tok0 = blockIdx.x * TMB;

    f32x4 acc[2][7];
    #pragma unroll
    for (int mi = 0; mi < 2; ++mi)
        #pragma unroll
        for (int nj = 0; nj < 7; ++nj)
            acc[mi][nj] = (f32x4){0.f, 0.f, 0.f, 0.f};

    for (int ch = 0; ch < NCHUNK; ++ch) {
        const int k0 = ch * KB;
        __syncthreads();                      // prev chunk's frag reads done
        // ---- stage x chunk (64 tok x 32 k) + f32 copy to out --------------
        #pragma unroll
        for (int i = 0; i < 2; ++i) {
            int u = t + 256 * i;              // 512 units of 4 f32
            int row = u >> 3, c4 = (u & 7) * 4;
            size_t g = (size_t)(tok0 + row) * DK + k0 + c4;
            float4 v = *(const float4*)(x + g);
            *(float4*)(out + g) = v;          // x_flat copy
            ushort4 h, lo; split4(v, h, lo);
            int off = swz(row, c4 * 2);
            *(ushort4*)(Ahi + off) = h;
            *(ushort4*)(Alo + off) = lo;
        }
        // ---- stage w chunk (224 exp x 32 k) -------------------------------
        #pragma unroll
        for (int i = 0; i < 7; ++i) {
            int u = t + 256 * i;              // 1792 units
            int row = u >> 3, c4 = (u & 7) * 4;
            float4 v = make_float4(0.f, 0.f, 0.f, 0.f);
            if (row < E) v = *(const float4*)(w + (size_t)row * DK + k0 + c4);
            ushort4 h, lo; split4(v, h, lo);
            int off = swz(row, c4 * 2);
            *(ushort4*)(Bhi + off) = h;
            *(ushort4*)(Blo + off) = lo;
        }
        __syncthreads();
        // ---- MFMA: 3-term split accumulation ------------------------------
        bf16x8 ah[2], al[2];
        #pragma unroll
        for (int mi = 0; mi < 2; ++mi) {
            int r = wm * 32 + mi * 16 + lrow;
            int off = swz(r, coff);
            ah[mi] = *(const bf16x8*)(Ahi + off);
            al[mi] = *(const bf16x8*)(Alo + off);
        }
        #pragma unroll
        for (int nj = 0; nj < 7; ++nj) {
            int r = (wn * 7 + nj) * 16 + lrow;
            int off = swz(r, coff);
            bf16x8 bh = *(const bf16x8*)(Bhi + off);
            bf16x8 bl = *(const bf16x8*)(Blo + off);
            #pragma unroll
            for (int mi = 0; mi < 2; ++mi) {
                acc[mi][nj] = __builtin_amdgcn_mfma_f32_16x16x32_bf16(ah[mi], bh, acc[mi][nj], 0, 0, 0);
                acc[mi][nj] = __builtin_amdgcn_mfma_f32_16x16x32_bf16(ah[mi], bl, acc[mi][nj], 0, 0, 0);
                acc[mi][nj] = __builtin_amdgcn_mfma_f32_16x16x32_bf16(al[mi], bh, acc[mi][nj], 0, 0, 0);
            }
        }
    }

    // -------- phase 2: two 32-token passes over LDS logits ------------------
    if (t < EPAD) ps_l[t] = 0.f;
    float* logits = (float*)smem4;            // 32 x LP f32 = 28.8 KB (aliases tiles)

    for (int pass = 0; pass < 2; ++pass) {
        __syncthreads();                      // prior LDS reads done
        if (wm == pass) {                     // 2 waves dump their C tiles
            #pragma unroll
            for (int mi = 0; mi < 2; ++mi)
                #pragma unroll
                for (int nj = 0; nj < 7; ++nj)
                    #pragma unroll
                    for (int rg = 0; rg < 4; ++rg) {
                        int rr = mi * 16 + (l >> 4) * 4 + rg;   // 0..31
                        int cc = wn * 112 + nj * 16 + (l & 15); // 0..223
                        logits[rr * LP + cc] = acc[mi][nj][rg];
                    }
        }
        __syncthreads();
        {   // 8 threads per token: top-2 + softmax denom
            int r = t >> 3, sub = t & 7;
            float m1 = -1e30f, m2 = -1e30f;
            int i1 = 0x7fffffff;
            for (int e = sub; e < E; e += 8) {
                float v = logits[r * LP + e];
                if (v > m1) { m2 = m1; m1 = v; i1 = e; }
                else if (v > m2) { m2 = v; }
            }
            #pragma unroll
            for (int mask = 1; mask < 8; mask <<= 1) {
                float om1 = __shfl_xor(m1, mask);
                float om2 = __shfl_xor(m2, mask);
                int   oi1 = __shfl_xor(i1, mask);
                if (om1 > m1 || (om1 == m1 && oi1 < i1)) {
                    m2 = fmaxf(m1, om2); m1 = om1; i1 = oi1;
                } else {
                    m2 = fmaxf(m2, om1);
                }
            }
            float s = 0.f;
            for (int e = sub; e < E; e += 8) s += __expf(logits[r * LP + e] - m1);
            #pragma unroll
            for (int mask = 1; mask < 8; mask <<= 1) s += __shfl_xor(s, mask);

            if (sub == 0) {
                float sinv = 1.0f / s;
                tok_m[r] = m1; tok_s[r] = sinv;
                int tok = tok0 + pass * 32 + r;
                out[(size_t)N * DK + tok]     = sinv;        // max prob
                out[(size_t)N * DK + N + tok] = (float)i1;   // expert index
                atomicAdd(&hist[i1], 1.0f);
                if (m1 - m2 < 1e-3f) {                       // ambiguous argmax
                    int pos = atomicAdd(flag_cnt, 1);
                    if (pos < flag_cap) flag_list[pos] = tok;
                }
            }
        }
        __syncthreads();
        if (t < E) {                          // thread = expert: no atomics
            float sum = 0.f;
            #pragma unroll 4
            for (int r = 0; r < 32; ++r)
                sum += __expf(logits[r * LP + t] - tok_m[r]) * tok_s[r];
            ps_l[t] += sum;
        }
    }
    __syncthreads();
    if (t < E) atomicAdd(&probsum_g[t], ps_l[t]);
}

// ------------------------------------------------------------- refine --------
// f64 recompute of all E dots for tokens with f32 top-2 gap < tau.
extern "C" __global__ void __launch_bounds__(256)
moe_refine(const float* __restrict__ x,
           const float* __restrict__ w,
           float* __restrict__ hist,
           const int* __restrict__ flag_cnt,
           const int* __restrict__ flag_list,
           int flag_cap,
           float* __restrict__ out,
           int N, int E)
{
    __shared__ float  xsh[DK];
    __shared__ double rv[256];
    __shared__ int    ri[256];
    int nf = *flag_cnt; if (nf > flag_cap) nf = flag_cap;
    const int tid = threadIdx.x;

    for (int li = blockIdx.x; li < nf; li += gridDim.x) {
        int tok = flag_list[li];
        for (int k = tid; k < DK; k += 256) xsh[k] = x[(size_t)tok * DK + k];
        __syncthreads();
        double a = -1e300;
        if (tid < E) {
            const float* wr = w + (size_t)tid * DK;
            double a0 = 0, a1 = 0, a2 = 0, a3 = 0;      // ILP-4 chains
            for (int k = 0; k < DK; k += 4) {
                a0 += (double)xsh[k]     * (double)wr[k];
                a1 += (double)xsh[k + 1] * (double)wr[k + 1];
                a2 += (double)xsh[k + 2] * (double)wr[k + 2];
                a3 += (double)xsh[k + 3] * (double)wr[k + 3];
            }
            a = (a0 + a1) + (a2 + a3);
        }
        rv[tid] = a; ri[tid] = tid;
        __syncthreads();
        for (int s = 128; s > 0; s >>= 1) {
            if (tid < s) {
                double vb = rv[tid + s]; int ib = ri[tid + s];
                double va = rv[tid];     int ia = ri[tid];
                if (vb > va || (vb == va && ib < ia)) { rv[tid] = vb; ri[tid] = ib; }
            }
            __syncthreads();
        }
        if (tid == 0) {
            int newi = ri[0];
            int oldi = (int)out[(size_t)N * DK + N + tok];
            if (newi != oldi) {
                atomicAdd(&hist[oldi], -1.0f);
                atomicAdd(&hist[newi],  1.0f);
                out[(size_t)N * DK + N + tok] = (float)newi;
            }
        }
        __syncthreads();
    }
}

// ------------------------------------------------------------ finalize -------
extern "C" __global__ void __launch_bounds__(256)
moe_final(const float* __restrict__ hist,
          const float* __restrict__ probsum,
          const float* __restrict__ ec_in,
          const float* __restrict__ gps_in,
          float* __restrict__ out,
          int N, int E)
{
    __shared__ double red[256];
    int t = threadIdx.x;
    double p = 0.0;
    if (t < E) p = (double)hist[t] * (double)probsum[t];
    red[t] = p;
    __syncthreads();
    for (int s = 128; s > 0; s >>= 1) {
        if (t < s) red[t] += red[t + s];
        __syncthreads();
    }
    size_t base = (size_t)N * DK + 2 * (size_t)N;
    if (t == 0) {
        double loss = (double)E * red[0] / ((double)N * (double)N);
        out[base] = (float)loss;
    }
    if (t < E) {
        out[base + 1 + t]     = 0.9f * ec_in[t]  + 0.1f * hist[t];
        out[base + 1 + E + t] = 0.9f * gps_in[t] + 0.1f * probsum[t];
    }
}

// ------------------------------------------------------------- launch --------
extern "C" void kernel_launch(void* const* d_in, const int* in_sizes, int n_in,
                              void* d_out, int out_size, void* d_ws, size_t ws_size,
                              hipStream_t stream)
{
    const float* x   = (const float*)d_in[0];
    const float* w   = (const float*)d_in[1];
    const float* ec  = (const float*)d_in[2];
    const float* gps = (const float*)d_in[3];
    float* out = (float*)d_out;

    int E = in_sizes[2];              // 209
    int N = in_sizes[0] / DK;         // 65536

    float* hist    = (float*)d_ws;
    float* probsum = hist + EPAD;
    int*   cnt     = (int*)(probsum + EPAD);
    int*   list    = cnt + 1;
    long long cap_ll = ((long long)ws_size - 4LL * (EPAD + EPAD + 1)) / 4;
    int cap = cap_ll < 0 ? 0 : (cap_ll > 65536 ? 65536 : (int)cap_ll);

    moe_init  <<<1,       256, 0, stream>>>(hist, probsum, cnt);
    moe_main  <<<N / TMB, 256, 0, stream>>>(x, w, out, hist, probsum, cnt, list, cap, N, E);
    moe_refine<<<256,     256, 0, stream>>>(x, w, hist, cnt, list, cap, out, N, E);
    moe_final <<<1,       256, 0, stream>>>(hist, probsum, ec, gps, out, N, E);
}

// Round 5
// 245.195 us; speedup vs baseline: 14.1602x; 1.0220x over previous
//
#include <hip/hip_runtime.h>

// ---------------- constants (B=8,S=8192 -> N=65536, D=512, E=209) ------------
#define DK 512         // feature dim
#define TMB 64         // tokens per block
#define KB 32          // K per chunk (= one MFMA K-step)
#define NCHUNK (DK / KB)   // 16
#define NPANEL 14          // expert panels of 16 -> EPAD
#define EPAD 224
#define LP 225             // logits row stride (f32), phase 2
#define WFRAG_ELEMS (EPAD * DK)   // 114688 bf16 per array

typedef __attribute__((ext_vector_type(8))) short bf16x8;   // 8 bf16 = 4 VGPR
typedef __attribute__((ext_vector_type(4))) float f32x4;

__device__ __forceinline__ unsigned short f2b(float f) {   // f32 -> bf16 RNE
    unsigned u = __float_as_uint(f);
    return (unsigned short)((u + 0x7fffu + ((u >> 16) & 1u)) >> 16);
}
__device__ __forceinline__ float b2f(unsigned short h) {
    return __uint_as_float((unsigned)h << 16);
}
__device__ __forceinline__ void split4(float4 v, ushort4& h, ushort4& lo) {
    h.x = f2b(v.x); h.y = f2b(v.y); h.z = f2b(v.z); h.w = f2b(v.w);
    lo.x = f2b(v.x - b2f(h.x)); lo.y = f2b(v.y - b2f(h.y));
    lo.z = f2b(v.z - b2f(h.z)); lo.w = f2b(v.w - b2f(h.w));
}
// swizzled byte offset in a [rows][32 bf16 = 64B] tile (m214 XOR pattern)
__device__ __forceinline__ int swz(int row, int colbyte) {
    return (row * 64 + colbyte) ^ ((row & 7) << 4);
}

// ---------------------------------------------------------------- init -------
extern "C" __global__ void moe_init(float* hist, float* probsum, int* cnt) {
    int t = threadIdx.x;
    if (t < EPAD) { hist[t] = 0.f; probsum[t] = 0.f; }
    if (t == 0) *cnt = 0;
}

// ---------------------------------------------------------------- prep -------
// One-time: w [E][DK] f32 -> fragment-major bf16 hi/lo arrays.
// Fragment order matches moe_main's B read: idx = ((ch*14+p)*64 + l)*8 + j
// holds w[p*16 + (l&15)][ch*32 + (l>>4)*8 + j].  16*14*64 = 14336 threads.
extern "C" __global__ void __launch_bounds__(256)
moe_prep(const float* __restrict__ w,
         unsigned short* __restrict__ wHi,
         unsigned short* __restrict__ wLo, int E)
{
    int g = blockIdx.x * 256 + threadIdx.x;      // 0..14335
    int l  = g & 63;
    int pc = g >> 6;                              // ch*14 + p
    int ch = pc / NPANEL;
    int p  = pc - ch * NPANEL;
    int e  = p * 16 + (l & 15);
    int k0 = ch * KB + (l >> 4) * 8;
    float4 v0 = make_float4(0.f,0.f,0.f,0.f), v1 = v0;
    if (e < E) {
        v0 = *(const float4*)(w + (size_t)e * DK + k0);
        v1 = *(const float4*)(w + (size_t)e * DK + k0 + 4);
    }
    ushort4 h0, l0, h1, l1;
    split4(v0, h0, l0); split4(v1, h1, l1);
    size_t off = (size_t)g * 8;
    *(ushort4*)(wHi + off)     = h0;
    *(ushort4*)(wHi + off + 4) = h1;
    *(ushort4*)(wLo + off)     = l0;
    *(ushort4*)(wLo + off + 4) = l1;
}

// ---------------------------------------------------------------- main -------
// 256 thr = 4 waves, wave grid 2x2: wm = token half (32 tok), wn = expert half
// (7 panels). A (x) staged hi/lo in LDS per K-chunk; B (w) fragments loaded
// straight global->reg from the precomputed fragment-major arrays (L2-resident,
// no conversion, no barriers, pipelines across the MFMA burst).
extern "C" __global__ void __launch_bounds__(256, 3)
moe_main(const float* __restrict__ x,
         const unsigned short* __restrict__ wHi,
         const unsigned short* __restrict__ wLo,
         float* __restrict__ out,
         float* __restrict__ hist,
         float* __restrict__ probsum_g,
         int* __restrict__ flag_cnt,
         int* __restrict__ flag_list,
         int flag_cap, int N, int E)
{
    __shared__ float logits_s[32 * LP];          // 28.8 KB; A tiles alias front
    __shared__ float ps_l[EPAD];
    __shared__ float tok_m[32], tok_s[32];
    char* Ahi = (char*)logits_s;                 // 64 x 64B = 4096
    char* Alo = (char*)logits_s + 4096;          // 4096

    const int t   = threadIdx.x;
    const int l   = t & 63;
    const int wid = t >> 6;
    const int wm  = wid >> 1;                    // token half
    const int wn  = wid & 1;                     // expert half
    const int lrow = l & 15;
    const int coff = (l >> 4) * 16;              // byte col of lane's frag
    const int tok0 = blockIdx.x * TMB;

    f32x4 acc[2][7];
    #pragma unroll
    for (int mi = 0; mi < 2; ++mi)
        #pragma unroll
        for (int nj = 0; nj < 7; ++nj)
            acc[mi][nj] = (f32x4){0.f, 0.f, 0.f, 0.f};

    for (int ch = 0; ch < NCHUNK; ++ch) {
        __syncthreads();                         // prev chunk's A reads done
        // ---- stage x chunk (64 tok x 32 k) + f32 copy to out --------------
        #pragma unroll
        for (int i = 0; i < 2; ++i) {
            int u = t + 256 * i;                 // 512 float4 units
            int row = u >> 3, c4 = (u & 7) * 4;
            size_t g = (size_t)(tok0 + row) * DK + ch * KB + c4;
            float4 v = *(const float4*)(x + g);
            *(float4*)(out + g) = v;             // x_flat copy
            ushort4 h, lo; split4(v, h, lo);
            int off = swz(row, c4 * 2);
            *(ushort4*)(Ahi + off) = h;
            *(ushort4*)(Alo + off) = lo;
        }
        __syncthreads();
        // ---- A frags from LDS, B frags straight from global (L2) ----------
        bf16x8 ah[2], al[2];
        #pragma unroll
        for (int mi = 0; mi < 2; ++mi) {
            int off = swz(wm * 32 + mi * 16 + lrow, coff);
            ah[mi] = *(const bf16x8*)(Ahi + off);
            al[mi] = *(const bf16x8*)(Alo + off);
        }
        #pragma unroll
        for (int p = 0; p < 7; ++p) {
            size_t boff = ((size_t)(ch * NPANEL + wn * 7 + p) * 64 + l) * 8;
            bf16x8 bh = *(const bf16x8*)(wHi + boff);
            bf16x8 bl = *(const bf16x8*)(wLo + boff);
            #pragma unroll
            for (int mi = 0; mi < 2; ++mi) {
                acc[mi][p] = __builtin_amdgcn_mfma_f32_16x16x32_bf16(ah[mi], bh, acc[mi][p], 0, 0, 0);
                acc[mi][p] = __builtin_amdgcn_mfma_f32_16x16x32_bf16(ah[mi], bl, acc[mi][p], 0, 0, 0);
                acc[mi][p] = __builtin_amdgcn_mfma_f32_16x16x32_bf16(al[mi], bh, acc[mi][p], 0, 0, 0);
            }
        }
    }

    // -------- phase 2: two 32-token passes over LDS logits ------------------
    if (t < EPAD) ps_l[t] = 0.f;
    float* logits = logits_s;

    for (int pass = 0; pass < 2; ++pass) {
        __syncthreads();                         // prior LDS reads done
        if (wm == pass) {                        // 2 waves dump their C tiles
            #pragma unroll
            for (int mi = 0; mi < 2; ++mi)
                #pragma unroll
                for (int nj = 0; nj < 7; ++nj)
                    #pragma unroll
                    for (int rg = 0; rg < 4; ++rg) {
                        int rr = mi * 16 + (l >> 4) * 4 + rg;   // 0..31
                        int cc = wn * 112 + nj * 16 + (l & 15); // 0..223
                        logits[rr * LP + cc] = acc[mi][nj][rg];
                    }
        }
        __syncthreads();
        {   // 8 threads per token: top-2 + softmax denom
            int r = t >> 3, sub = t & 7;
            float m1 = -1e30f, m2 = -1e30f;
            int i1 = 0x7fffffff;
            for (int e = sub; e < E; e += 8) {
                float v = logits[r * LP + e];
                if (v > m1) { m2 = m1; m1 = v; i1 = e; }
                else if (v > m2) { m2 = v; }
            }
            #pragma unroll
            for (int mask = 1; mask < 8; mask <<= 1) {
                float om1 = __shfl_xor(m1, mask);
                float om2 = __shfl_xor(m2, mask);
                int   oi1 = __shfl_xor(i1, mask);
                if (om1 > m1 || (om1 == m1 && oi1 < i1)) {
                    m2 = fmaxf(m1, om2); m1 = om1; i1 = oi1;
                } else {
                    m2 = fmaxf(m2, om1);
                }
            }
            float s = 0.f;
            for (int e = sub; e < E; e += 8) s += __expf(logits[r * LP + e] - m1);
            #pragma unroll
            for (int mask = 1; mask < 8; mask <<= 1) s += __shfl_xor(s, mask);

            if (sub == 0) {
                float sinv = 1.0f / s;
                tok_m[r] = m1; tok_s[r] = sinv;
                int tok = tok0 + pass * 32 + r;
                out[(size_t)N * DK + tok]     = sinv;        // max prob
                out[(size_t)N * DK + N + tok] = (float)i1;   // expert index
                atomicAdd(&hist[i1], 1.0f);
                if (m1 - m2 < 1e-3f) {                       // ambiguous argmax
                    int pos = atomicAdd(flag_cnt, 1);
                    if (pos < flag_cap) flag_list[pos] = tok;
                }
            }
        }
        __syncthreads();
        if (t < E) {                             // thread = expert: no atomics
            float sum = 0.f;
            #pragma unroll 4
            for (int r = 0; r < 32; ++r)
                sum += __expf(logits[r * LP + t] - tok_m[r]) * tok_s[r];
            ps_l[t] += sum;
        }
    }
    __syncthreads();
    if (t < E) atomicAdd(&probsum_g[t], ps_l[t]);
}

// ------------------------------------------------------------- refine --------
// f64 recompute (original f32 w!) for tokens with f32 top-2 gap < tau.
extern "C" __global__ void __launch_bounds__(256)
moe_refine(const float* __restrict__ x,
           const float* __restrict__ w,
           float* __restrict__ hist,
           const int* __restrict__ flag_cnt,
           const int* __restrict__ flag_list,
           int flag_cap,
           float* __restrict__ out,
           int N, int E)
{
    __shared__ float  xsh[DK];
    __shared__ double rv[256];
    __shared__ int    ri[256];
    int nf = *flag_cnt; if (nf > flag_cap) nf = flag_cap;
    const int tid = threadIdx.x;

    for (int li = blockIdx.x; li < nf; li += gridDim.x) {
        int tok = flag_list[li];
        for (int k = tid; k < DK; k += 256) xsh[k] = x[(size_t)tok * DK + k];
        __syncthreads();
        double a = -1e300;
        if (tid < E) {
            const float* wr = w + (size_t)tid * DK;
            double a0 = 0, a1 = 0, a2 = 0, a3 = 0;
            for (int k = 0; k < DK; k += 4) {
                a0 += (double)xsh[k]     * (double)wr[k];
                a1 += (double)xsh[k + 1] * (double)wr[k + 1];
                a2 += (double)xsh[k + 2] * (double)wr[k + 2];
                a3 += (double)xsh[k + 3] * (double)wr[k + 3];
            }
            a = (a0 + a1) + (a2 + a3);
        }
        rv[tid] = a; ri[tid] = tid;
        __syncthreads();
        for (int s = 128; s > 0; s >>= 1) {
            if (tid < s) {
                double vb = rv[tid + s]; int ib = ri[tid + s];
                double va = rv[tid];     int ia = ri[tid];
                if (vb > va || (vb == va && ib < ia)) { rv[tid] = vb; ri[tid] = ib; }
            }
            __syncthreads();
        }
        if (tid == 0) {
            int newi = ri[0];
            int oldi = (int)out[(size_t)N * DK + N + tok];
            if (newi != oldi) {
                atomicAdd(&hist[oldi], -1.0f);
                atomicAdd(&hist[newi],  1.0f);
                out[(size_t)N * DK + N + tok] = (float)newi;
            }
        }
        __syncthreads();
    }
}

// ------------------------------------------------------------ finalize -------
extern "C" __global__ void __launch_bounds__(256)
moe_final(const float* __restrict__ hist,
          const float* __restrict__ probsum,
          const float* __restrict__ ec_in,
          const float* __restrict__ gps_in,
          float* __restrict__ out,
          int N, int E)
{
    __shared__ double red[256];
    int t = threadIdx.x;
    double p = 0.0;
    if (t < E) p = (double)hist[t] * (double)probsum[t];
    red[t] = p;
    __syncthreads();
    for (int s = 128; s > 0; s >>= 1) {
        if (t < s) red[t] += red[t + s];
        __syncthreads();
    }
    size_t base = (size_t)N * DK + 2 * (size_t)N;
    if (t == 0) {
        double loss = (double)E * red[0] / ((double)N * (double)N);
        out[base] = (float)loss;
    }
    if (t < E) {
        out[base + 1 + t]     = 0.9f * ec_in[t]  + 0.1f * hist[t];
        out[base + 1 + E + t] = 0.9f * gps_in[t] + 0.1f * probsum[t];
    }
}

// ------------------------------------------------------------- launch --------
extern "C" void kernel_launch(void* const* d_in, const int* in_sizes, int n_in,
                              void* d_out, int out_size, void* d_ws, size_t ws_size,
                              hipStream_t stream)
{
    const float* x   = (const float*)d_in[0];
    const float* w   = (const float*)d_in[1];
    const float* ec  = (const float*)d_in[2];
    const float* gps = (const float*)d_in[3];
    float* out = (float*)d_out;

    int E = in_sizes[2];              // 209
    int N = in_sizes[0] / DK;         // 65536

    unsigned short* wHi = (unsigned short*)d_ws;
    unsigned short* wLo = wHi + WFRAG_ELEMS;
    float* hist    = (float*)(wLo + WFRAG_ELEMS);
    float* probsum = hist + EPAD;
    int*   cnt     = (int*)(probsum + EPAD);
    int*   list    = cnt + 1;
    long long used = 2LL * WFRAG_ELEMS * 2 + 4LL * (2 * EPAD + 1);
    long long cap_ll = ((long long)ws_size - used) / 4;
    int cap = cap_ll < 0 ? 0 : (cap_ll > 65536 ? 65536 : (int)cap_ll);

    moe_prep  <<<56,      256, 0, stream>>>(w, wHi, wLo, E);
    moe_init  <<<1,       256, 0, stream>>>(hist, probsum, cnt);
    moe_main  <<<N / TMB, 256, 0, stream>>>(x, wHi, wLo, out, hist, probsum, cnt, list, cap, N, E);
    moe_refine<<<256,     256, 0, stream>>>(x, w, hist, cnt, list, cap, out, N, E);
    moe_final <<<1,       256, 0, stream>>>(hist, probsum, ec, gps, out, N, E);
}

// Round 6
// 191.550 us; speedup vs baseline: 18.1259x; 1.2801x over previous
//
#include <hip/hip_runtime.h>

// ---------------- constants (B=8,S=8192 -> N=65536, D=512, E=209) ------------
#define DK 512         // feature dim
#define TMB 64         // tokens per block
#define KB 32          // K per chunk (= one MFMA K-step)
#define NCHUNK (DK / KB)   // 16
#define NPANEL 14          // expert panels of 16 -> EPAD
#define EPAD 224
#define LP 225             // logits row stride (f32), phase 2
#define WFRAG_ELEMS (EPAD * DK)   // 114688 bf16 per array

typedef __attribute__((ext_vector_type(8))) short bf16x8;   // 8 bf16 = 4 VGPR
typedef __attribute__((ext_vector_type(4))) float f32x4;

__device__ __forceinline__ unsigned short f2b(float f) {   // f32 -> bf16 RNE
    unsigned u = __float_as_uint(f);
    return (unsigned short)((u + 0x7fffu + ((u >> 16) & 1u)) >> 16);
}
__device__ __forceinline__ float b2f(unsigned short h) {
    return __uint_as_float((unsigned)h << 16);
}
// RNE split (used in prep only)
__device__ __forceinline__ void split4(float4 v, ushort4& h, ushort4& lo) {
    h.x = f2b(v.x); h.y = f2b(v.y); h.z = f2b(v.z); h.w = f2b(v.w);
    lo.x = f2b(v.x - b2f(h.x)); lo.y = f2b(v.y - b2f(h.y));
    lo.z = f2b(v.z - b2f(h.z)); lo.w = f2b(v.w - b2f(h.w));
}
// cheap split: truncation hi (residual exact), RNE lo.  ~5 ops/elem.
__device__ __forceinline__ void split4t(float4 v, ushort4& h, ushort4& lo) {
    unsigned ux = __float_as_uint(v.x), uy = __float_as_uint(v.y);
    unsigned uz = __float_as_uint(v.z), uw = __float_as_uint(v.w);
    h.x = (unsigned short)(ux >> 16); h.y = (unsigned short)(uy >> 16);
    h.z = (unsigned short)(uz >> 16); h.w = (unsigned short)(uw >> 16);
    lo.x = f2b(v.x - __uint_as_float(ux & 0xffff0000u));
    lo.y = f2b(v.y - __uint_as_float(uy & 0xffff0000u));
    lo.z = f2b(v.z - __uint_as_float(uz & 0xffff0000u));
    lo.w = f2b(v.w - __uint_as_float(uw & 0xffff0000u));
}
// swizzled byte offset in a [rows][32 bf16 = 64B] tile (m214 XOR pattern)
__device__ __forceinline__ int swz(int row, int colbyte) {
    return (row * 64 + colbyte) ^ ((row & 7) << 4);
}

// ---------------------------------------------------------------- init -------
extern "C" __global__ void moe_init(float* hist, float* probsum, int* cnt) {
    int t = threadIdx.x;
    if (t < EPAD) { hist[t] = 0.f; probsum[t] = 0.f; }
    if (t == 0) *cnt = 0;
}

// ---------------------------------------------------------------- prep -------
// One-time: w [E][DK] f32 -> fragment-major bf16 hi/lo arrays.
// idx = ((ch*14+p)*64 + l)*8 + j  holds  w[p*16+(l&15)][ch*32+(l>>4)*8+j].
extern "C" __global__ void __launch_bounds__(256)
moe_prep(const float* __restrict__ w,
         unsigned short* __restrict__ wHi,
         unsigned short* __restrict__ wLo, int E)
{
    int g = blockIdx.x * 256 + threadIdx.x;      // 0..14335
    int l  = g & 63;
    int pc = g >> 6;                              // ch*14 + p
    int ch = pc / NPANEL;
    int p  = pc - ch * NPANEL;
    int e  = p * 16 + (l & 15);
    int k0 = ch * KB + (l >> 4) * 8;
    float4 v0 = make_float4(0.f,0.f,0.f,0.f), v1 = v0;
    if (e < E) {
        v0 = *(const float4*)(w + (size_t)e * DK + k0);
        v1 = *(const float4*)(w + (size_t)e * DK + k0 + 4);
    }
    ushort4 h0, l0, h1, l1;
    split4(v0, h0, l0); split4(v1, h1, l1);
    size_t off = (size_t)g * 8;
    *(ushort4*)(wHi + off)     = h0;
    *(ushort4*)(wHi + off + 4) = h1;
    *(ushort4*)(wLo + off)     = l0;
    *(ushort4*)(wLo + off + 4) = l1;
}

// ---------------------------------------------------------------- main -------
// 4 waves, grid 2x2 (wm token half, wn expert half).  Pipelined K-loop:
// depth-2 reg prefetch of x + double-buffered LDS A + 1 barrier/chunk.
extern "C" __global__ void __launch_bounds__(256, 4)
moe_main(const float* __restrict__ x,
         const unsigned short* __restrict__ wHi,
         const unsigned short* __restrict__ wLo,
         float* __restrict__ out,
         float* __restrict__ hist,
         float* __restrict__ probsum_g,
         int* __restrict__ flag_cnt,
         int* __restrict__ flag_list,
         int flag_cap, int N, int E)
{
    __shared__ float logits_s[32 * LP];          // 28.8 KB; A dbuf aliases front
    __shared__ float ps_l[EPAD];
    __shared__ float tok_m[32], tok_s[32];
    char* base = (char*)logits_s;
    char* AhiB[2] = { base,        base + 8192  };
    char* AloB[2] = { base + 4096, base + 12288 };

    const int t   = threadIdx.x;
    const int l   = t & 63;
    const int wid = t >> 6;
    const int wm  = wid >> 1;                    // token half
    const int wn  = wid & 1;                     // expert half
    const int lrow = l & 15;
    const int coff = (l >> 4) * 16;              // byte col of lane's frag
    const int tok0 = blockIdx.x * TMB;

    const int urow[2] = { t >> 3, (t + 256) >> 3 };
    const int uc4 [2] = { (t & 7) * 4, (t & 7) * 4 };

    f32x4 acc[2][7];
    #pragma unroll
    for (int mi = 0; mi < 2; ++mi)
        #pragma unroll
        for (int nj = 0; nj < 7; ++nj)
            acc[mi][nj] = (f32x4){0.f, 0.f, 0.f, 0.f};

    float4 pre[2][2];                            // [parity][i] prefetch regs

    // ---- prologue: load ch0, ch1; stage ch0 ----
    #pragma unroll
    for (int i = 0; i < 2; ++i)
        pre[0][i] = *(const float4*)(x + (size_t)(tok0 + urow[i]) * DK + 0 * KB + uc4[i]);
    #pragma unroll
    for (int i = 0; i < 2; ++i)
        pre[1][i] = *(const float4*)(x + (size_t)(tok0 + urow[i]) * DK + 1 * KB + uc4[i]);
    #pragma unroll
    for (int i = 0; i < 2; ++i) {
        float4 v = pre[0][i];
        *(float4*)(out + (size_t)(tok0 + urow[i]) * DK + 0 * KB + uc4[i]) = v;
        ushort4 h, lo; split4t(v, h, lo);
        int off = swz(urow[i], uc4[i] * 2);
        *(ushort4*)(AhiB[0] + off) = h;
        *(ushort4*)(AloB[0] + off) = lo;
    }
    __syncthreads();

    // ---- pipelined K loop: at iter ch, buf[ch&1]=ch ready, pre[1-(ch&1)]=ch+1
    #pragma unroll
    for (int ch = 0; ch < NCHUNK; ++ch) {
        const int p = ch & 1;
        // 1) issue loads for ch+2 into just-freed pre[p]
        if (ch + 2 < NCHUNK) {
            #pragma unroll
            for (int i = 0; i < 2; ++i)
                pre[p][i] = *(const float4*)(x + (size_t)(tok0 + urow[i]) * DK + (ch + 2) * KB + uc4[i]);
        }
        // 2) convert+stage ch+1 into buf[1-p]; emit f32 x_flat copy
        if (ch + 1 < NCHUNK) {
            #pragma unroll
            for (int i = 0; i < 2; ++i) {
                float4 v = pre[1 - p][i];
                *(float4*)(out + (size_t)(tok0 + urow[i]) * DK + (ch + 1) * KB + uc4[i]) = v;
                ushort4 h, lo; split4t(v, h, lo);
                int off = swz(urow[i], uc4[i] * 2);
                *(ushort4*)(AhiB[1 - p] + off) = h;
                *(ushort4*)(AloB[1 - p] + off) = lo;
            }
        }
        // 3) MFMA burst on buf[p] (chunk ch); B frags straight from global (L2)
        {
            bf16x8 ah[2], al[2];
            #pragma unroll
            for (int mi = 0; mi < 2; ++mi) {
                int off = swz(wm * 32 + mi * 16 + lrow, coff);
                ah[mi] = *(const bf16x8*)(AhiB[p] + off);
                al[mi] = *(const bf16x8*)(AloB[p] + off);
            }
            #pragma unroll
            for (int pp = 0; pp < 7; ++pp) {
                size_t boff = ((size_t)(ch * NPANEL + wn * 7 + pp) * 64 + l) * 8;
                bf16x8 bh = *(const bf16x8*)(wHi + boff);
                bf16x8 bl = *(const bf16x8*)(wLo + boff);
                #pragma unroll
                for (int mi = 0; mi < 2; ++mi) {
                    acc[mi][pp] = __builtin_amdgcn_mfma_f32_16x16x32_bf16(ah[mi], bh, acc[mi][pp], 0, 0, 0);
                    acc[mi][pp] = __builtin_amdgcn_mfma_f32_16x16x32_bf16(ah[mi], bl, acc[mi][pp], 0, 0, 0);
                    acc[mi][pp] = __builtin_amdgcn_mfma_f32_16x16x32_bf16(al[mi], bh, acc[mi][pp], 0, 0, 0);
                }
            }
        }
        // 4) one barrier per chunk: buf[p] reads done, buf[1-p] writes visible
        __syncthreads();
    }

    // -------- phase 2: two 32-token passes over LDS logits ------------------
    if (t < EPAD) ps_l[t] = 0.f;
    float* logits = logits_s;

    for (int pass = 0; pass < 2; ++pass) {
        __syncthreads();
        if (wm == pass) {                        // 2 waves dump their C tiles
            #pragma unroll
            for (int mi = 0; mi < 2; ++mi)
                #pragma unroll
                for (int nj = 0; nj < 7; ++nj)
                    #pragma unroll
                    for (int rg = 0; rg < 4; ++rg) {
                        int rr = mi * 16 + (l >> 4) * 4 + rg;   // 0..31
                        int cc = wn * 112 + nj * 16 + (l & 15); // 0..223
                        logits[rr * LP + cc] = acc[mi][nj][rg];
                    }
        }
        __syncthreads();
        {   // 8 threads per token: top-2 + softmax denom
            int r = t >> 3, sub = t & 7;
            float m1 = -1e30f, m2 = -1e30f;
            int i1 = 0x7fffffff;
            for (int e = sub; e < E; e += 8) {
                float v = logits[r * LP + e];
                if (v > m1) { m2 = m1; m1 = v; i1 = e; }
                else if (v > m2) { m2 = v; }
            }
            #pragma unroll
            for (int mask = 1; mask < 8; mask <<= 1) {
                float om1 = __shfl_xor(m1, mask);
                float om2 = __shfl_xor(m2, mask);
                int   oi1 = __shfl_xor(i1, mask);
                if (om1 > m1 || (om1 == m1 && oi1 < i1)) {
                    m2 = fmaxf(m1, om2); m1 = om1; i1 = oi1;
                } else {
                    m2 = fmaxf(m2, om1);
                }
            }
            float s = 0.f;
            for (int e = sub; e < E; e += 8) s += __expf(logits[r * LP + e] - m1);
            #pragma unroll
            for (int mask = 1; mask < 8; mask <<= 1) s += __shfl_xor(s, mask);

            if (sub == 0) {
                float sinv = 1.0f / s;
                tok_m[r] = m1; tok_s[r] = sinv;
                int tok = tok0 + pass * 32 + r;
                out[(size_t)N * DK + tok]     = sinv;        // max prob
                out[(size_t)N * DK + N + tok] = (float)i1;   // expert index
                atomicAdd(&hist[i1], 1.0f);
                if (m1 - m2 < 1e-4f) {                       // ambiguous argmax
                    int pos = atomicAdd(flag_cnt, 1);
                    if (pos < flag_cap) flag_list[pos] = tok;
                }
            }
        }
        __syncthreads();
        if (t < E) {                             // thread = expert: no atomics
            float sum = 0.f;
            #pragma unroll 4
            for (int r = 0; r < 32; ++r)
                sum += __expf(logits[r * LP + t] - tok_m[r]) * tok_s[r];
            ps_l[t] += sum;
        }
    }
    __syncthreads();
    if (t < E) atomicAdd(&probsum_g[t], ps_l[t]);
}

// ------------------------------------------------------------- refine --------
// f64 recompute (original f32 w) for tokens with f32 top-2 gap < tau.
extern "C" __global__ void __launch_bounds__(256)
moe_refine(const float* __restrict__ x,
           const float* __restrict__ w,
           float* __restrict__ hist,
           const int* __restrict__ flag_cnt,
           const int* __restrict__ flag_list,
           int flag_cap,
           float* __restrict__ out,
           int N, int E)
{
    __shared__ float  xsh[DK];
    __shared__ double rv[256];
    __shared__ int    ri[256];
    int nf = *flag_cnt; if (nf > flag_cap) nf = flag_cap;
    const int tid = threadIdx.x;

    for (int li = blockIdx.x; li < nf; li += gridDim.x) {
        int tok = flag_list[li];
        for (int k = tid; k < DK; k += 256) xsh[k] = x[(size_t)tok * DK + k];
        __syncthreads();
        double a = -1e300;
        if (tid < E) {
            const float* wr = w + (size_t)tid * DK;
            double a0 = 0, a1 = 0, a2 = 0, a3 = 0;
            for (int k = 0; k < DK; k += 4) {
                a0 += (double)xsh[k]     * (double)wr[k];
                a1 += (double)xsh[k + 1] * (double)wr[k + 1];
                a2 += (double)xsh[k + 2] * (double)wr[k + 2];
                a3 += (double)xsh[k + 3] * (double)wr[k + 3];
            }
            a = (a0 + a1) + (a2 + a3);
        }
        rv[tid] = a; ri[tid] = tid;
        __syncthreads();
        for (int s = 128; s > 0; s >>= 1) {
            if (tid < s) {
                double vb = rv[tid + s]; int ib = ri[tid + s];
                double va = rv[tid];     int ia = ri[tid];
                if (vb > va || (vb == va && ib < ia)) { rv[tid] = vb; ri[tid] = ib; }
            }
            __syncthreads();
        }
        if (tid == 0) {
            int newi = ri[0];
            int oldi = (int)out[(size_t)N * DK + N + tok];
            if (newi != oldi) {
                atomicAdd(&hist[oldi], -1.0f);
                atomicAdd(&hist[newi],  1.0f);
                out[(size_t)N * DK + N + tok] = (float)newi;
            }
        }
        __syncthreads();
    }
}

// ------------------------------------------------------------ finalize -------
extern "C" __global__ void __launch_bounds__(256)
moe_final(const float* __restrict__ hist,
          const float* __restrict__ probsum,
          const float* __restrict__ ec_in,
          const float* __restrict__ gps_in,
          float* __restrict__ out,
          int N, int E)
{
    __shared__ double red[256];
    int t = threadIdx.x;
    double p = 0.0;
    if (t < E) p = (double)hist[t] * (double)probsum[t];
    red[t] = p;
    __syncthreads();
    for (int s = 128; s > 0; s >>= 1) {
        if (t < s) red[t] += red[t + s];
        __syncthreads();
    }
    size_t base = (size_t)N * DK + 2 * (size_t)N;
    if (t == 0) {
        double loss = (double)E * red[0] / ((double)N * (double)N);
        out[base] = (float)loss;
    }
    if (t < E) {
        out[base + 1 + t]     = 0.9f * ec_in[t]  + 0.1f * hist[t];
        out[base + 1 + E + t] = 0.9f * gps_in[t] + 0.1f * probsum[t];
    }
}

// ------------------------------------------------------------- launch --------
extern "C" void kernel_launch(void* const* d_in, const int* in_sizes, int n_in,
                              void* d_out, int out_size, void* d_ws, size_t ws_size,
                              hipStream_t stream)
{
    const float* x   = (const float*)d_in[0];
    const float* w   = (const float*)d_in[1];
    const float* ec  = (const float*)d_in[2];
    const float* gps = (const float*)d_in[3];
    float* out = (float*)d_out;

    int E = in_sizes[2];              // 209
    int N = in_sizes[0] / DK;         // 65536

    unsigned short* wHi = (unsigned short*)d_ws;
    unsigned short* wLo = wHi + WFRAG_ELEMS;
    float* hist    = (float*)(wLo + WFRAG_ELEMS);
    float* probsum = hist + EPAD;
    int*   cnt     = (int*)(probsum + EPAD);
    int*   list    = cnt + 1;
    long long used = 2LL * WFRAG_ELEMS * 2 + 4LL * (2 * EPAD + 1);
    long long cap_ll = ((long long)ws_size - used) / 4;
    int cap = cap_ll < 0 ? 0 : (cap_ll > 65536 ? 65536 : (int)cap_ll);

    moe_prep  <<<56,      256, 0, stream>>>(w, wHi, wLo, E);
    moe_init  <<<1,       256, 0, stream>>>(hist, probsum, cnt);
    moe_main  <<<N / TMB, 256, 0, stream>>>(x, wHi, wLo, out, hist, probsum, cnt, list, cap, N, E);
    moe_refine<<<256,     256, 0, stream>>>(x, w, hist, cnt, list, cap, out, N, E);
    moe_final <<<1,       256, 0, stream>>>(hist, probsum, ec, gps, out, N, E);
}